// Round 12
// baseline (1262.500 us; speedup 1.0000x reference)
//
#include <hip/hip_runtime.h>
#include <math.h>

#define DD 128      // hidden dim
#define ANND 64     // annotation dim
#define NSTEPS 5
#define NTYPES 4
#define NCLS 10

typedef __attribute__((ext_vector_type(8))) short short8v;  // 8 bf16
typedef __attribute__((ext_vector_type(4))) float f32x4;

// split fp32 into hi+lo bf16 (RNE both)
__device__ __forceinline__ void split2(float x, unsigned short& hi, unsigned short& lo) {
  unsigned u = __float_as_uint(x);
  unsigned hb = (u + 0x7FFFu + ((u >> 16) & 1u)) >> 16;
  hi = (unsigned short)hb;
  float r = x - __uint_as_float(hb << 16);
  unsigned v = __float_as_uint(r);
  lo = (unsigned short)((v + 0x7FFFu + ((v >> 16) & 1u)) >> 16);
}

__device__ __forceinline__ float bf2f(unsigned short u) {
  return __uint_as_float(((unsigned)u) << 16);
}
__device__ __forceinline__ float rec2(const unsigned short* hi, const unsigned short* lo, size_t i) {
  return bf2f(hi[i]) + bf2f(lo[i]);
}
__device__ __forceinline__ float lo16f(unsigned u) { return __uint_as_float(u << 16); }
__device__ __forceinline__ float hi16f(unsigned u) { return __uint_as_float(u & 0xffff0000u); }

// async global->LDS, 16B per lane (dest = wave-uniform base + lane*16)
__device__ __forceinline__ void gload16(const unsigned short* g, unsigned short* l) {
  __builtin_amdgcn_global_load_lds(
      (const __attribute__((address_space(1))) unsigned int*)(const void*)g,
      (__attribute__((address_space(3))) unsigned int*)(void*)l, 16, 0, 0);
}

// h = [ann | 0] as split planes; zero-fill padded rows [n, npad)
__global__ void k_init(const float* __restrict__ ann,
    unsigned short* __restrict__ hhi, unsigned short* __restrict__ hlo, int n, int npad) {
  int idx = blockIdx.x * blockDim.x + threadIdx.x;
  if (idx >= npad * DD) return;
  int node = idx >> 7, d = idx & 127;
  float v = (node < n && d < ANND) ? ann[node * ANND + d] : 0.0f;
  unsigned short hi, lo; split2(v, hi, lo);
  hhi[idx] = hi; hlo[idx] = lo;
}

// ---------- CSR build (by dst), once per launch ----------
__global__ void k_deg4(const int* __restrict__ dst, const int* __restrict__ et,
    int* __restrict__ deg4, int e) {
  int i = blockIdx.x * blockDim.x + threadIdx.x;
  if (i < e) atomicAdd(&deg4[dst[i] * 4 + et[i]], 1);
}

__global__ __launch_bounds__(1024) void k_scan(const int* __restrict__ deg4,
    int* __restrict__ base, int n) {
  __shared__ int part[1024];
  int t = threadIdx.x;
  int chunk = (n + 1023) >> 10;
  int s = t * chunk, e = min(n, s + chunk);
  int sum = 0;
  for (int i = s; i < e; ++i) {
    const int4 d4 = *(const int4*)(deg4 + (size_t)i * 4);
    sum += d4.x + d4.y + d4.z + d4.w;
  }
  part[t] = sum;
  __syncthreads();
  int own = sum;
  for (int off = 1; off < 1024; off <<= 1) {
    int v = (t >= off) ? part[t - off] : 0;
    __syncthreads();
    part[t] += v;
    __syncthreads();
  }
  int run = part[t] - own;
  for (int i = s; i < e; ++i) {
    base[i] = run;
    const int4 d4 = *(const int4*)(deg4 + (size_t)i * 4);
    run += d4.x + d4.y + d4.z + d4.w;
  }
  if (s < n && e == n) base[n] = run;
}

__global__ void k_place(const int* __restrict__ src, const int* __restrict__ dst,
    const int* __restrict__ et, const int* __restrict__ base, int* __restrict__ cursor,
    int* __restrict__ cpack, int e) {
  int i = blockIdx.x * blockDim.x + threadIdx.x;
  if (i >= e) return;
  int d = dst[i];
  int pos = base[d] + atomicAdd(&cursor[d], 1);
  cpack[pos] = src[i] | (et[i] << 18);
}

// ---------- per-type neighbor sums: one WAVE per node, shfl-broadcast indices ----------
__global__ void k_aggh(const unsigned* __restrict__ hhiU, const unsigned* __restrict__ hloU,
    const int* __restrict__ base, const int* __restrict__ cpack,
    unsigned* __restrict__ A3hiU, unsigned* __restrict__ A3loU, int nbase, int cc) {
  int w = threadIdx.x >> 6;
  int lane = threadIdx.x & 63;
  int local = blockIdx.x * 4 + w;
  if (local >= cc) return;
  int node = nbase + local;
  int s = base[node], e = base[node + 1];
  float a0x = 0.f, a0y = 0.f, a1x = 0.f, a1y = 0.f;
  float a2x = 0.f, a2y = 0.f, a3x = 0.f, a3y = 0.f;
  for (int t0 = s; t0 < e; t0 += 64) {
    int cnt = min(64, e - t0);
    int mypk = (t0 + lane < e) ? cpack[t0 + lane] : 0;
    int i = 0;
    for (; i + 4 <= cnt; i += 4) {
      int pk0 = __shfl(mypk, i), pk1 = __shfl(mypk, i + 1);
      int pk2 = __shfl(mypk, i + 2), pk3 = __shfl(mypk, i + 3);
      unsigned uh0 = hhiU[(size_t)(pk0 & 0x3ffff) * 64 + lane];
      unsigned ul0 = hloU[(size_t)(pk0 & 0x3ffff) * 64 + lane];
      unsigned uh1 = hhiU[(size_t)(pk1 & 0x3ffff) * 64 + lane];
      unsigned ul1 = hloU[(size_t)(pk1 & 0x3ffff) * 64 + lane];
      unsigned uh2 = hhiU[(size_t)(pk2 & 0x3ffff) * 64 + lane];
      unsigned ul2 = hloU[(size_t)(pk2 & 0x3ffff) * 64 + lane];
      unsigned uh3 = hhiU[(size_t)(pk3 & 0x3ffff) * 64 + lane];
      unsigned ul3 = hloU[(size_t)(pk3 & 0x3ffff) * 64 + lane];
      float v0x = lo16f(uh0) + lo16f(ul0), v0y = hi16f(uh0) + hi16f(ul0);
      float v1x = lo16f(uh1) + lo16f(ul1), v1y = hi16f(uh1) + hi16f(ul1);
      float v2x = lo16f(uh2) + lo16f(ul2), v2y = hi16f(uh2) + hi16f(ul2);
      float v3x = lo16f(uh3) + lo16f(ul3), v3y = hi16f(uh3) + hi16f(ul3);
      int t;
      t = pk0 >> 18;
      if (t == 0) { a0x += v0x; a0y += v0y; } else if (t == 1) { a1x += v0x; a1y += v0y; }
      else if (t == 2) { a2x += v0x; a2y += v0y; } else { a3x += v0x; a3y += v0y; }
      t = pk1 >> 18;
      if (t == 0) { a0x += v1x; a0y += v1y; } else if (t == 1) { a1x += v1x; a1y += v1y; }
      else if (t == 2) { a2x += v1x; a2y += v1y; } else { a3x += v1x; a3y += v1y; }
      t = pk2 >> 18;
      if (t == 0) { a0x += v2x; a0y += v2y; } else if (t == 1) { a1x += v2x; a1y += v2y; }
      else if (t == 2) { a2x += v2x; a2y += v2y; } else { a3x += v2x; a3y += v2y; }
      t = pk3 >> 18;
      if (t == 0) { a0x += v3x; a0y += v3y; } else if (t == 1) { a1x += v3x; a1y += v3y; }
      else if (t == 2) { a2x += v3x; a2y += v3y; } else { a3x += v3x; a3y += v3y; }
    }
    for (; i < cnt; ++i) {
      int pk = __shfl(mypk, i);
      unsigned uh = hhiU[(size_t)(pk & 0x3ffff) * 64 + lane];
      unsigned ul = hloU[(size_t)(pk & 0x3ffff) * 64 + lane];
      float vx = lo16f(uh) + lo16f(ul), vy = hi16f(uh) + hi16f(ul);
      int t = pk >> 18;
      if (t == 0) { a0x += vx; a0y += vy; } else if (t == 1) { a1x += vx; a1y += vy; }
      else if (t == 2) { a2x += vx; a2y += vy; } else { a3x += vx; a3y += vy; }
    }
  }
  size_t bu = (size_t)local * 256 + lane;
  unsigned short h0, l0, h1, l1;
  split2(a0x, h0, l0); split2(a0y, h1, l1);
  A3hiU[bu] = (unsigned)h0 | ((unsigned)h1 << 16);
  A3loU[bu] = (unsigned)l0 | ((unsigned)l1 << 16);
  split2(a1x, h0, l0); split2(a1y, h1, l1);
  A3hiU[bu + 64] = (unsigned)h0 | ((unsigned)h1 << 16);
  A3loU[bu + 64] = (unsigned)l0 | ((unsigned)l1 << 16);
  split2(a2x, h0, l0); split2(a2y, h1, l1);
  A3hiU[bu + 128] = (unsigned)h0 | ((unsigned)h1 << 16);
  A3loU[bu + 128] = (unsigned)l0 | ((unsigned)l1 << 16);
  split2(a3x, h0, l0); split2(a3y, h1, l1);
  A3hiU[bu + 192] = (unsigned)h0 | ((unsigned)h1 << 16);
  A3loU[bu + 192] = (unsigned)l0 | ((unsigned)l1 << 16);
}

// ---------- fused-weight prep (once per launch) ----------
// VW[c][k*128+d] = sum_o W_ih[c][o] * W_lin[k][o][d]   (384 x 512, fp32)
__global__ void k_fusew(const float* __restrict__ Wih, const float* __restrict__ Wlin,
    float* __restrict__ VW) {
  int idx = blockIdx.x * blockDim.x + threadIdx.x;
  if (idx >= 384 * 512) return;
  int c = idx >> 9, kd = idx & 511;
  int k = kd >> 7, d = kd & 127;
  const float* wi = Wih + (size_t)c * DD;
  const float* wl = Wlin + (size_t)k * DD * DD + d;
  float s = 0.f;
  for (int o = 0; o < DD; ++o) s += wi[o] * wl[(size_t)o * DD];
  VW[idx] = s;
}

// Wbig[512][640] with PERMUTED rows: c_new = (d>>5)*128 + ((d>>4)&1)*64 + g*16 + (d&15)
// original row c = g*128+d; value: gates over K = [A3(512) | H(128)], gn zero on H, hn zero on A3
__global__ void k_wbig(const float* __restrict__ VW, const float* __restrict__ Whh,
    unsigned short* __restrict__ WbH, unsigned short* __restrict__ WbL) {
  int idx = blockIdx.x * blockDim.x + threadIdx.x;
  if (idx >= 512 * 640) return;
  int c = idx / 640, k = idx % 640;
  float v;
  if (c < 256)      v = (k < 512) ? VW[(size_t)c * 512 + k] : Whh[(size_t)c * DD + (k - 512)];
  else if (c < 384) v = (k < 512) ? VW[(size_t)c * 512 + k] : 0.f;
  else              v = (k < 512) ? 0.f : Whh[(size_t)(c - 128) * DD + (k - 512)];
  int g = c >> 7, d = c & 127;
  int cn = ((d >> 5) << 7) + (((d >> 4) & 1) << 6) + (g << 4) + (d & 15);
  unsigned short h, l; split2(v, h, l);
  WbH[(size_t)cn * 640 + k] = h;
  WbL[(size_t)cn * 640 + k] = l;
}

// bias_big[512] (layout g*128+d) and cb4[4][512]
__global__ void k_fuseb(const float* __restrict__ Wih, const float* __restrict__ bih,
    const float* __restrict__ bhh, const float* __restrict__ blin,
    float* __restrict__ bias_big, float* __restrict__ cb4) {
  int c = blockIdx.x * blockDim.x + threadIdx.x;
  if (c >= 512) return;
  float b;
  if (c < 256) b = bih[c] + bhh[c];
  else if (c < 384) b = bih[c];
  else b = bhh[c - 128];
  bias_big[c] = b;
  for (int k = 0; k < NTYPES; ++k) {
    float s = 0.f;
    if (c < 384) {
      const float* wi = Wih + (size_t)c * DD;
      const float* bl = blin + (size_t)k * DD;
      for (int o = 0; o < DD; ++o) s += wi[o] * bl[o];
    }
    cb4[k * 512 + c] = s;
  }
}

// ---------- step kernel v3: 2-phase double-buffered LDS (T3 minimum pipeline) ----------
// 64 rows x 256 cols, 4 waves. blockIdx.x = col-half, blockIdx.y = row tile.
// Per iter: STAGE(next -> buf^1) BEFORE ds_read+MFMA(buf); ONE barrier per iter.
// Wave w stages W gate-subblock w; skipped when that gate is structurally zero.
__global__ __launch_bounds__(256) void k_gru6(
    const unsigned short* __restrict__ A3hi, const unsigned short* __restrict__ A3lo,
    const unsigned short* __restrict__ Hhi, const unsigned short* __restrict__ Hlo,
    const unsigned short* __restrict__ WbH, const unsigned short* __restrict__ WbL,
    const float* __restrict__ bias_big, const float* __restrict__ cb4,
    const int* __restrict__ deg4,
    unsigned short* __restrict__ Ohi, unsigned short* __restrict__ Olo,
    int nbase, int cc) {
  __shared__ unsigned short ldsX[2 * 4096];    // per buf: XH(2048) | XL(2048)  (16 KiB total)
  __shared__ unsigned short ldsW[2 * 16384];   // per buf: WH(8192) | WL(8192)  (64 KiB total)
  int tid = threadIdx.x;
  int wc = tid >> 6, lane = tid & 63;
  int lr = lane & 15, lk = lane >> 4;
  int rowbase = blockIdx.y * 64;
  int ytile = blockIdx.x;
  int wtb = ytile * 256;                       // permuted Wbig row base
  f32x4 acc[4][4];                             // [mm][gate]
  #pragma unroll
  for (int mm = 0; mm < 4; ++mm)
    #pragma unroll
    for (int g = 0; g < 4; ++g) acc[mm][g] = (f32x4){0.f, 0.f, 0.f, 0.f};

  int srow = tid >> 2, sc0 = tid & 3;
  int xcs = sc0 ^ (srow & 3);                  // XOR pre-swizzled source chunk
  int wwb = (tid & ~63) * 8;                   // wave-uniform LDS base offset (shorts)

  // stage tile k0 into buffer buf
  auto STAGE = [&](int k0, int buf) {
    {  // X: 64 rows x 32 shorts x 2 planes
      const unsigned short *xsH, *xsL;
      if (k0 < 512) {
        size_t off = (size_t)(rowbase + srow) * 512 + k0 + xcs * 8;
        xsH = A3hi + off; xsL = A3lo + off;
      } else {
        size_t off = (size_t)(nbase + rowbase + srow) * DD + (k0 - 512) + xcs * 8;
        xsH = Hhi + off; xsL = Hlo + off;
      }
      unsigned short* xdst = ldsX + buf * 4096 + wwb;
      gload16(xsH, xdst);
      gload16(xsL, xdst + 2048);
    }
    // W: wave wc stages gate-subblock wc (rows i*64 + [16wc,16wc+16) for i=0..3).
    // Skip when that gate's K-slice is structurally zero.
    int skipgrp = (k0 < 512) ? 3 : 2;
    if (wc != skipgrp) {
      #pragma unroll
      for (int i = 0; i < 4; ++i) {
        int wrow = i * 64 + srow;
        int wcs = sc0 ^ (wrow & 3);
        size_t woff = (size_t)(wtb + wrow) * 640 + k0 + wcs * 8;
        unsigned short* wdst = ldsW + buf * 16384 + i * 2048 + wwb;
        gload16(WbH + woff, wdst);
        gload16(WbL + woff, wdst + 8192);
      }
    }
  };

  STAGE(0, 0);
  __syncthreads();                             // drain prologue stage (vmcnt0 at barrier)

  for (int it = 0; it < 20; ++it) {
    int k0 = it * 32;
    int buf = it & 1;
    if (it + 1 < 20) STAGE((it + 1) * 32, buf ^ 1);   // issue next-tile loads FIRST

    int nnSkip = (k0 < 512) ? 3 : 2;           // hn zero on A3-range, gn zero on H-range
    const unsigned short* bx = ldsX + buf * 4096;
    const unsigned short* bw = ldsW + buf * 16384;
    short8v xh[4], xl[4];
    #pragma unroll
    for (int mm = 0; mm < 4; ++mm) {
      int r = mm * 16 + lr;
      int a = r * 32 + ((lk ^ (r & 3)) << 3);
      xh[mm] = *(const short8v*)(bx + a);
      xl[mm] = *(const short8v*)(bx + 2048 + a);
    }
    #pragma unroll
    for (int nn = 0; nn < 4; ++nn) {
      if (nn == nnSkip) continue;
      int rw = wc * 64 + nn * 16 + lr;
      int a = rw * 32 + ((lk ^ (rw & 3)) << 3);
      short8v wh = *(const short8v*)(bw + a);
      short8v wl = *(const short8v*)(bw + 8192 + a);
      #pragma unroll
      for (int mm = 0; mm < 4; ++mm) {
        acc[mm][nn] = __builtin_amdgcn_mfma_f32_16x16x32_bf16(xh[mm], wh, acc[mm][nn], 0, 0, 0);
        acc[mm][nn] = __builtin_amdgcn_mfma_f32_16x16x32_bf16(xh[mm], wl, acc[mm][nn], 0, 0, 0);
        acc[mm][nn] = __builtin_amdgcn_mfma_f32_16x16x32_bf16(xl[mm], wh, acc[mm][nn], 0, 0, 0);
      }
    }
    __syncthreads();   // one barrier/iter: drains next-tile stage + orders LDS reuse
  }

  // epilogue: thread owns d = ytile*64 + wc*16 + lr, gates nn=0..3
  int d = ytile * 64 + wc * 16 + lr;
  float bsr = bias_big[d], bsz = bias_big[128 + d];
  float bgn = bias_big[256 + d], bhn = bias_big[384 + d];
  float cbr[4], cbz[4], cbn[4];
  #pragma unroll
  for (int k = 0; k < 4; ++k) {
    cbr[k] = cb4[k * 512 + d];
    cbz[k] = cb4[k * 512 + 128 + d];
    cbn[k] = cb4[k * 512 + 256 + d];
  }
  #pragma unroll
  for (int mm = 0; mm < 4; ++mm) {
    #pragma unroll
    for (int j = 0; j < 4; ++j) {
      int row = rowbase + mm * 16 + lk * 4 + j;
      if (row < cc) {
        int4 dg = *(const int4*)(deg4 + (size_t)row * 4);
        float s_r = acc[mm][0][j] + bsr + dg.x * cbr[0] + dg.y * cbr[1] + dg.z * cbr[2] + dg.w * cbr[3];
        float s_z = acc[mm][1][j] + bsz + dg.x * cbz[0] + dg.y * cbz[1] + dg.z * cbz[2] + dg.w * cbz[3];
        float g_n = acc[mm][2][j] + bgn + dg.x * cbn[0] + dg.y * cbn[1] + dg.z * cbn[2] + dg.w * cbn[3];
        float h_n = acc[mm][3][j] + bhn;
        float r = 1.f / (1.f + expf(-s_r));
        float z = 1.f / (1.f + expf(-s_z));
        float nt = tanhf(g_n + r * h_n);
        size_t gidx = (size_t)(nbase + row) * DD + d;
        float hv = (1.f - z) * nt + z * rec2(Hhi, Hlo, gidx);
        unsigned short uh, ul; split2(hv, uh, ul);
        Ohi[gidx] = uh; Olo[gidx] = ul;
      }
    }
  }
}

// ---------- readout ----------
__global__ void k_gate(const unsigned short* __restrict__ hhi,
    const unsigned short* __restrict__ hlo, const float* __restrict__ ann,
    const float* __restrict__ gw, const float* __restrict__ gb,
    float* __restrict__ gate, int n) {
  int gt = blockIdx.x * blockDim.x + threadIdx.x;
  int wv = gt >> 6;
  int lane = threadIdx.x & 63;
  if (wv >= n) return;
  float p = rec2(hhi, hlo, (size_t)wv * DD + lane) * gw[lane]
          + rec2(hhi, hlo, (size_t)wv * DD + 64 + lane) * gw[64 + lane]
          + ann[(size_t)wv * ANND + lane] * gw[128 + lane];
  for (int off = 32; off; off >>= 1) p += __shfl_down(p, off);
  if (lane == 0) gate[wv] = p + gb[0];
}

// sorted node2graph -> segment bounds via boundary detection (no atomics)
__global__ void k_bounds(const int* __restrict__ n2g, int* __restrict__ startg,
    int* __restrict__ endg, int n) {
  int i = blockIdx.x * blockDim.x + threadIdx.x;
  if (i >= n) return;
  int g = n2g[i];
  if (i == 0 || n2g[i - 1] != g) startg[g] = i;
  if (i == n - 1 || n2g[i + 1] != g) endg[g] = i + 1;
}

// per-graph softmax max + 1/denominator
__global__ __launch_bounds__(256) void k_mden(const float* __restrict__ gate,
    const int* __restrict__ startg, const int* __restrict__ endg,
    float* __restrict__ mg, float* __restrict__ invg) {
  __shared__ float red[256];
  int g = blockIdx.x;
  int s = startg[g], e = endg[g];
  int tid = threadIdx.x;
  float m = -1e30f;
  for (int i = s + tid; i < e; i += 256) m = fmaxf(m, gate[i]);
  red[tid] = m; __syncthreads();
  for (int off = 128; off; off >>= 1) {
    if (tid < off) red[tid] = fmaxf(red[tid], red[tid + off]);
    __syncthreads();
  }
  m = red[0];
  __syncthreads();
  float sum = 0.f;
  for (int i = s + tid; i < e; i += 256) sum += expf(gate[i] - m);
  red[tid] = sum; __syncthreads();
  for (int off = 128; off; off >>= 1) {
    if (tid < off) red[tid] += red[tid + off];
    __syncthreads();
  }
  if (tid == 0) { mg[g] = m; invg[g] = (s < e) ? 1.f / red[0] : 0.f; }
}

// weighted readout; grid (B, 2): y=0 h-dims (packed uint pairs), y=1 ann-dims
__global__ __launch_bounds__(256) void k_pool2(const float* __restrict__ gate,
    const unsigned* __restrict__ hhiU, const unsigned* __restrict__ hloU,
    const float* __restrict__ ann, const int* __restrict__ startg,
    const int* __restrict__ endg, const float* __restrict__ mg,
    const float* __restrict__ invg, float* __restrict__ readout) {
  __shared__ float redx[256], redy[256];
  int g = blockIdx.x;
  int s = startg[g], e = endg[g];
  int nl = threadIdx.x >> 6, lane = threadIdx.x & 63;
  float m = mg[g], inv = invg[g];
  if (blockIdx.y == 0) {
    float ax = 0.f, ay = 0.f;
    for (int i = s + nl; i < e; i += 4) {
      float al = expf(gate[i] - m) * inv;
      unsigned uh = hhiU[(size_t)i * 64 + lane];
      unsigned ul = hloU[(size_t)i * 64 + lane];
      ax += al * (lo16f(uh) + lo16f(ul));
      ay += al * (hi16f(uh) + hi16f(ul));
    }
    redx[threadIdx.x] = ax; redy[threadIdx.x] = ay;
    __syncthreads();
    if (nl == 0) {
      float sx = redx[lane] + redx[64 + lane] + redx[128 + lane] + redx[192 + lane];
      float sy = redy[lane] + redy[64 + lane] + redy[128 + lane] + redy[192 + lane];
      readout[g * (DD + ANND) + 2 * lane] = sx;
      readout[g * (DD + ANND) + 2 * lane + 1] = sy;
    }
  } else {
    float acc = 0.f;
    for (int i = s + nl; i < e; i += 4) {
      float al = expf(gate[i] - m) * inv;
      acc += al * ann[(size_t)i * ANND + lane];
    }
    redx[threadIdx.x] = acc;
    __syncthreads();
    if (nl == 0)
      readout[g * (DD + ANND) + DD + lane] =
          redx[lane] + redx[64 + lane] + redx[128 + lane] + redx[192 + lane];
  }
}

__global__ void k_logits(const float* __restrict__ readout, const float* __restrict__ ow,
    const float* __restrict__ ob, const int* __restrict__ labels,
    float* __restrict__ out, int B) {
  __shared__ float lsum[64];
  int g = threadIdx.x;
  float loss_c = 0.f;
  if (g < B) {
    float lg[NCLS];
    float mx = -1e30f;
    int best = 0;
    for (int c = 0; c < NCLS; ++c) {
      float acc = ob[c];
      const float* r = readout + g * (DD + ANND);
      const float* w = ow + c * (DD + ANND);
      for (int d = 0; d < DD + ANND; ++d) acc += r[d] * w[d];
      lg[c] = acc;
      if (acc > mx) { mx = acc; best = c; }
    }
    float se = 0.f;
    for (int c = 0; c < NCLS; ++c) se += expf(lg[c] - mx);
    float lse = mx + logf(se);
    loss_c = -(lg[labels[g]] - lse);
    out[1 + g] = (float)best;
  }
  lsum[threadIdx.x] = loss_c;
  __syncthreads();
  for (int off = 32; off; off >>= 1) {
    if (threadIdx.x < off) lsum[threadIdx.x] += lsum[threadIdx.x + off];
    __syncthreads();
  }
  if (threadIdx.x == 0) out[0] = lsum[0] / (float)B;
}

extern "C" void kernel_launch(void* const* d_in, const int* in_sizes, int n_in,
                              void* d_out, int out_size, void* d_ws, size_t ws_size,
                              hipStream_t stream) {
  const float* annotation = (const float*)d_in[0];
  const int*   src        = (const int*)d_in[1];
  const int*   dst        = (const int*)d_in[2];
  const int*   et         = (const int*)d_in[3];
  const int*   n2g        = (const int*)d_in[4];
  const int*   labels     = (const int*)d_in[5];
  const float* W_lin      = (const float*)d_in[6];
  const float* b_lin      = (const float*)d_in[7];
  const float* W_ih       = (const float*)d_in[8];
  const float* W_hh       = (const float*)d_in[9];
  const float* b_ih       = (const float*)d_in[10];
  const float* b_hh       = (const float*)d_in[11];
  const float* gate_w     = (const float*)d_in[12];
  const float* gate_b     = (const float*)d_in[13];
  const float* out_w      = (const float*)d_in[14];
  const float* out_b      = (const float*)d_in[15];

  int N = in_sizes[0] / ANND;
  int E = in_sizes[1];
  int B = in_sizes[5];
  int Np = (N + 127) & ~127;

  // ---- workspace budget ----
  auto rup = [](size_t b) { return (b + 255) & ~(size_t)255; };
  size_t fixed = 0;
  fixed += 4 * rup((size_t)Np * DD * 2);           // h ping-pong planes
  fixed += rup((size_t)N * 4);                     // gate
  fixed += rup((size_t)B * (DD + ANND) * 4);       // readout
  fixed += 4 * rup((size_t)B * 4);                 // startg, endg, mg, invg
  fixed += rup((size_t)(N + 1) * 4);               // base
  fixed += rup((size_t)N * 4);                     // cursor
  fixed += rup((size_t)N * 16);                    // deg4
  fixed += rup((size_t)E * 4);                     // cpack
  fixed += rup(384 * 512 * 4);                     // VW
  fixed += 2 * rup(512 * 640 * 2);                 // WbH, WbL
  fixed += rup(512 * 4) + rup(4 * 512 * 4);        // bias_big, cb4
  size_t slack = 1 << 20;
  size_t avail = (ws_size > fixed + slack) ? ws_size - fixed - slack : 0;
  long long ch = (long long)(avail / 2048);        // A3 planes per node
  int CH = (int)((ch / 128) * 128);
  if (CH < 128) CH = 128;
  if (CH > Np) CH = Np;

  char* wsP = (char*)d_ws;
  auto alloc = [&](size_t bytes) -> void* {
    void* p = (void*)wsP;
    wsP += (bytes + 255) & ~(size_t)255;
    return p;
  };
  unsigned short* hP_hi[2], *hP_lo[2];
  hP_hi[0] = (unsigned short*)alloc((size_t)Np * DD * 2);
  hP_lo[0] = (unsigned short*)alloc((size_t)Np * DD * 2);
  hP_hi[1] = (unsigned short*)alloc((size_t)Np * DD * 2);
  hP_lo[1] = (unsigned short*)alloc((size_t)Np * DD * 2);
  float* gate = (float*)alloc((size_t)N * 4);
  float* readout = (float*)alloc((size_t)B * (DD + ANND) * 4);
  int* startg = (int*)alloc((size_t)B * 4);
  int* endg   = (int*)alloc((size_t)B * 4);
  float* mg   = (float*)alloc((size_t)B * 4);
  float* invg = (float*)alloc((size_t)B * 4);
  int* base   = (int*)alloc((size_t)(N + 1) * 4);
  int* cursor = (int*)alloc((size_t)N * 4);
  int* deg4   = (int*)alloc((size_t)N * 16);
  int* cpack  = (int*)alloc((size_t)E * 4);
  float* VW   = (float*)alloc(384 * 512 * 4);
  unsigned short* WbH = (unsigned short*)alloc(512 * 640 * 2);
  unsigned short* WbL = (unsigned short*)alloc(512 * 640 * 2);
  float* bias_big = (float*)alloc(512 * 4);
  float* cb4  = (float*)alloc(4 * 512 * 4);
  unsigned short* A3hi = (unsigned short*)alloc((size_t)CH * 512 * 2);
  unsigned short* A3lo = (unsigned short*)alloc((size_t)CH * 512 * 2);

  // init + CSR + fused-weight prep (once per launch)
  k_init<<<(Np * DD + 255) / 256, 256, 0, stream>>>(annotation, hP_hi[0], hP_lo[0], N, Np);
  hipMemsetAsync(cursor, 0, (size_t)N * 4, stream);
  hipMemsetAsync(deg4, 0, (size_t)N * 16, stream);
  hipMemsetAsync(startg, 0x7f, (size_t)B * 4, stream);
  hipMemsetAsync(endg, 0, (size_t)B * 4, stream);
  k_deg4<<<(E + 255) / 256, 256, 0, stream>>>(dst, et, deg4, E);
  k_scan<<<1, 1024, 0, stream>>>(deg4, base, N);
  k_place<<<(E + 255) / 256, 256, 0, stream>>>(src, dst, et, base, cursor, cpack, E);
  k_bounds<<<(N + 255) / 256, 256, 0, stream>>>(n2g, startg, endg, N);
  k_fusew<<<(384 * 512 + 255) / 256, 256, 0, stream>>>(W_ih, W_lin, VW);
  k_wbig<<<(512 * 640 + 255) / 256, 256, 0, stream>>>(VW, W_hh, WbH, WbL);
  k_fuseb<<<2, 256, 0, stream>>>(W_ih, b_ih, b_hh, b_lin, bias_big, cb4);

  int cur = 0;
  for (int s = 0; s < NSTEPS; ++s) {
    int nxt = cur ^ 1;
    for (int nbase = 0; nbase < N; nbase += CH) {
      int cc = min(CH, N - nbase);
      int cgrid = (cc + 63) / 64;
      k_aggh<<<(cc + 3) / 4, 256, 0, stream>>>(
          (const unsigned*)hP_hi[cur], (const unsigned*)hP_lo[cur], base, cpack,
          (unsigned*)A3hi, (unsigned*)A3lo, nbase, cc);
      k_gru6<<<dim3(2, cgrid), 256, 0, stream>>>(A3hi, A3lo,
          hP_hi[cur], hP_lo[cur], WbH, WbL, bias_big, cb4,
          deg4 + (size_t)nbase * 4, hP_hi[nxt], hP_lo[nxt], nbase, cc);
    }
    cur ^= 1;
  }

  k_gate<<<(N * 64 + 255) / 256, 256, 0, stream>>>(
      hP_hi[cur], hP_lo[cur], annotation, gate_w, gate_b, gate, N);
  k_mden<<<B, 256, 0, stream>>>(gate, startg, endg, mg, invg);
  k_pool2<<<dim3(B, 2), 256, 0, stream>>>(gate, (const unsigned*)hP_hi[cur],
      (const unsigned*)hP_lo[cur], annotation, startg, endg, mg, invg, readout);
  k_logits<<<1, 64, 0, stream>>>(readout, out_w, out_b, labels, (float*)d_out, B);
}

// Round 13
// 1253.747 us; speedup vs baseline: 1.0070x; 1.0070x over previous
//
#include <hip/hip_runtime.h>
#include <math.h>

#define DD 128      // hidden dim
#define ANND 64     // annotation dim
#define NSTEPS 5
#define NTYPES 4
#define NCLS 10

typedef __attribute__((ext_vector_type(8))) short short8v;  // 8 bf16
typedef __attribute__((ext_vector_type(4))) float f32x4;

// split fp32 into hi+lo bf16 (RNE both)
__device__ __forceinline__ void split2(float x, unsigned short& hi, unsigned short& lo) {
  unsigned u = __float_as_uint(x);
  unsigned hb = (u + 0x7FFFu + ((u >> 16) & 1u)) >> 16;
  hi = (unsigned short)hb;
  float r = x - __uint_as_float(hb << 16);
  unsigned v = __float_as_uint(r);
  lo = (unsigned short)((v + 0x7FFFu + ((v >> 16) & 1u)) >> 16);
}

__device__ __forceinline__ float bf2f(unsigned short u) {
  return __uint_as_float(((unsigned)u) << 16);
}
__device__ __forceinline__ float rec2(const unsigned short* hi, const unsigned short* lo, size_t i) {
  return bf2f(hi[i]) + bf2f(lo[i]);
}
__device__ __forceinline__ float lo16f(unsigned u) { return __uint_as_float(u << 16); }
__device__ __forceinline__ float hi16f(unsigned u) { return __uint_as_float(u & 0xffff0000u); }

// async global->LDS, 16B per lane (dest = wave-uniform base + lane*16)
__device__ __forceinline__ void gload16(const unsigned short* g, unsigned short* l) {
  __builtin_amdgcn_global_load_lds(
      (const __attribute__((address_space(1))) unsigned int*)(const void*)g,
      (__attribute__((address_space(3))) unsigned int*)(void*)l, 16, 0, 0);
}

// h = [ann | 0] as split planes; zero-fill padded rows [n, npad)
__global__ void k_init(const float* __restrict__ ann,
    unsigned short* __restrict__ hhi, unsigned short* __restrict__ hlo, int n, int npad) {
  int idx = blockIdx.x * blockDim.x + threadIdx.x;
  if (idx >= npad * DD) return;
  int node = idx >> 7, d = idx & 127;
  float v = (node < n && d < ANND) ? ann[node * ANND + d] : 0.0f;
  unsigned short hi, lo; split2(v, hi, lo);
  hhi[idx] = hi; hlo[idx] = lo;
}

// ---------- CSR build (by dst), once per launch ----------
__global__ void k_deg4(const int* __restrict__ dst, const int* __restrict__ et,
    int* __restrict__ deg4, int e) {
  int i = blockIdx.x * blockDim.x + threadIdx.x;
  if (i < e) atomicAdd(&deg4[dst[i] * 4 + et[i]], 1);
}

__global__ __launch_bounds__(1024) void k_scan(const int* __restrict__ deg4,
    int* __restrict__ base, int n) {
  __shared__ int part[1024];
  int t = threadIdx.x;
  int chunk = (n + 1023) >> 10;
  int s = t * chunk, e = min(n, s + chunk);
  int sum = 0;
  for (int i = s; i < e; ++i) {
    const int4 d4 = *(const int4*)(deg4 + (size_t)i * 4);
    sum += d4.x + d4.y + d4.z + d4.w;
  }
  part[t] = sum;
  __syncthreads();
  int own = sum;
  for (int off = 1; off < 1024; off <<= 1) {
    int v = (t >= off) ? part[t - off] : 0;
    __syncthreads();
    part[t] += v;
    __syncthreads();
  }
  int run = part[t] - own;
  for (int i = s; i < e; ++i) {
    base[i] = run;
    const int4 d4 = *(const int4*)(deg4 + (size_t)i * 4);
    run += d4.x + d4.y + d4.z + d4.w;
  }
  if (s < n && e == n) base[n] = run;
}

__global__ void k_place(const int* __restrict__ src, const int* __restrict__ dst,
    const int* __restrict__ et, const int* __restrict__ base, int* __restrict__ cursor,
    int* __restrict__ cpack, int e) {
  int i = blockIdx.x * blockDim.x + threadIdx.x;
  if (i >= e) return;
  int d = dst[i];
  int pos = base[d] + atomicAdd(&cursor[d], 1);
  cpack[pos] = src[i] | (et[i] << 18);
}

// ---------- per-type neighbor sums: one WAVE per node, shfl-broadcast indices ----------
__global__ void k_aggh(const unsigned* __restrict__ hhiU, const unsigned* __restrict__ hloU,
    const int* __restrict__ base, const int* __restrict__ cpack,
    unsigned* __restrict__ A3hiU, unsigned* __restrict__ A3loU, int nbase, int cc) {
  int w = threadIdx.x >> 6;
  int lane = threadIdx.x & 63;
  int local = blockIdx.x * 4 + w;
  if (local >= cc) return;
  int node = nbase + local;
  int s = base[node], e = base[node + 1];
  float a0x = 0.f, a0y = 0.f, a1x = 0.f, a1y = 0.f;
  float a2x = 0.f, a2y = 0.f, a3x = 0.f, a3y = 0.f;
  for (int t0 = s; t0 < e; t0 += 64) {
    int cnt = min(64, e - t0);
    int mypk = (t0 + lane < e) ? cpack[t0 + lane] : 0;
    int i = 0;
    for (; i + 4 <= cnt; i += 4) {
      int pk0 = __shfl(mypk, i), pk1 = __shfl(mypk, i + 1);
      int pk2 = __shfl(mypk, i + 2), pk3 = __shfl(mypk, i + 3);
      unsigned uh0 = hhiU[(size_t)(pk0 & 0x3ffff) * 64 + lane];
      unsigned ul0 = hloU[(size_t)(pk0 & 0x3ffff) * 64 + lane];
      unsigned uh1 = hhiU[(size_t)(pk1 & 0x3ffff) * 64 + lane];
      unsigned ul1 = hloU[(size_t)(pk1 & 0x3ffff) * 64 + lane];
      unsigned uh2 = hhiU[(size_t)(pk2 & 0x3ffff) * 64 + lane];
      unsigned ul2 = hloU[(size_t)(pk2 & 0x3ffff) * 64 + lane];
      unsigned uh3 = hhiU[(size_t)(pk3 & 0x3ffff) * 64 + lane];
      unsigned ul3 = hloU[(size_t)(pk3 & 0x3ffff) * 64 + lane];
      float v0x = lo16f(uh0) + lo16f(ul0), v0y = hi16f(uh0) + hi16f(ul0);
      float v1x = lo16f(uh1) + lo16f(ul1), v1y = hi16f(uh1) + hi16f(ul1);
      float v2x = lo16f(uh2) + lo16f(ul2), v2y = hi16f(uh2) + hi16f(ul2);
      float v3x = lo16f(uh3) + lo16f(ul3), v3y = hi16f(uh3) + hi16f(ul3);
      int t;
      t = pk0 >> 18;
      if (t == 0) { a0x += v0x; a0y += v0y; } else if (t == 1) { a1x += v0x; a1y += v0y; }
      else if (t == 2) { a2x += v0x; a2y += v0y; } else { a3x += v0x; a3y += v0y; }
      t = pk1 >> 18;
      if (t == 0) { a0x += v1x; a0y += v1y; } else if (t == 1) { a1x += v1x; a1y += v1y; }
      else if (t == 2) { a2x += v1x; a2y += v1y; } else { a3x += v1x; a3y += v1y; }
      t = pk2 >> 18;
      if (t == 0) { a0x += v2x; a0y += v2y; } else if (t == 1) { a1x += v2x; a1y += v2y; }
      else if (t == 2) { a2x += v2x; a2y += v2y; } else { a3x += v2x; a3y += v2y; }
      t = pk3 >> 18;
      if (t == 0) { a0x += v3x; a0y += v3y; } else if (t == 1) { a1x += v3x; a1y += v3y; }
      else if (t == 2) { a2x += v3x; a2y += v3y; } else { a3x += v3x; a3y += v3y; }
    }
    for (; i < cnt; ++i) {
      int pk = __shfl(mypk, i);
      unsigned uh = hhiU[(size_t)(pk & 0x3ffff) * 64 + lane];
      unsigned ul = hloU[(size_t)(pk & 0x3ffff) * 64 + lane];
      float vx = lo16f(uh) + lo16f(ul), vy = hi16f(uh) + hi16f(ul);
      int t = pk >> 18;
      if (t == 0) { a0x += vx; a0y += vy; } else if (t == 1) { a1x += vx; a1y += vy; }
      else if (t == 2) { a2x += vx; a2y += vy; } else { a3x += vx; a3y += vy; }
    }
  }
  size_t bu = (size_t)local * 256 + lane;
  unsigned short h0, l0, h1, l1;
  split2(a0x, h0, l0); split2(a0y, h1, l1);
  A3hiU[bu] = (unsigned)h0 | ((unsigned)h1 << 16);
  A3loU[bu] = (unsigned)l0 | ((unsigned)l1 << 16);
  split2(a1x, h0, l0); split2(a1y, h1, l1);
  A3hiU[bu + 64] = (unsigned)h0 | ((unsigned)h1 << 16);
  A3loU[bu + 64] = (unsigned)l0 | ((unsigned)l1 << 16);
  split2(a2x, h0, l0); split2(a2y, h1, l1);
  A3hiU[bu + 128] = (unsigned)h0 | ((unsigned)h1 << 16);
  A3loU[bu + 128] = (unsigned)l0 | ((unsigned)l1 << 16);
  split2(a3x, h0, l0); split2(a3y, h1, l1);
  A3hiU[bu + 192] = (unsigned)h0 | ((unsigned)h1 << 16);
  A3loU[bu + 192] = (unsigned)l0 | ((unsigned)l1 << 16);
}

// ---------- fused-weight prep (once per launch) ----------
// VW[c][k*128+d] = sum_o W_ih[c][o] * W_lin[k][o][d]   (384 x 512, fp32)
__global__ void k_fusew(const float* __restrict__ Wih, const float* __restrict__ Wlin,
    float* __restrict__ VW) {
  int idx = blockIdx.x * blockDim.x + threadIdx.x;
  if (idx >= 384 * 512) return;
  int c = idx >> 9, kd = idx & 511;
  int k = kd >> 7, d = kd & 127;
  const float* wi = Wih + (size_t)c * DD;
  const float* wl = Wlin + (size_t)k * DD * DD + d;
  float s = 0.f;
  for (int o = 0; o < DD; ++o) s += wi[o] * wl[(size_t)o * DD];
  VW[idx] = s;
}

// Wbig[512][640] with PERMUTED rows: c_new = (d>>5)*128 + ((d>>4)&1)*64 + g*16 + (d&15)
// original row c = g*128+d; value: gates over K = [A3(512) | H(128)], gn zero on H, hn zero on A3
__global__ void k_wbig(const float* __restrict__ VW, const float* __restrict__ Whh,
    unsigned short* __restrict__ WbH, unsigned short* __restrict__ WbL) {
  int idx = blockIdx.x * blockDim.x + threadIdx.x;
  if (idx >= 512 * 640) return;
  int c = idx / 640, k = idx % 640;
  float v;
  if (c < 256)      v = (k < 512) ? VW[(size_t)c * 512 + k] : Whh[(size_t)c * DD + (k - 512)];
  else if (c < 384) v = (k < 512) ? VW[(size_t)c * 512 + k] : 0.f;
  else              v = (k < 512) ? 0.f : Whh[(size_t)(c - 128) * DD + (k - 512)];
  int g = c >> 7, d = c & 127;
  int cn = ((d >> 5) << 7) + (((d >> 4) & 1) << 6) + (g << 4) + (d & 15);
  unsigned short h, l; split2(v, h, l);
  WbH[(size_t)cn * 640 + k] = h;
  WbL[(size_t)cn * 640 + k] = l;
}

// bias_big[512] (layout g*128+d) and cb4[4][512]
__global__ void k_fuseb(const float* __restrict__ Wih, const float* __restrict__ bih,
    const float* __restrict__ bhh, const float* __restrict__ blin,
    float* __restrict__ bias_big, float* __restrict__ cb4) {
  int c = blockIdx.x * blockDim.x + threadIdx.x;
  if (c >= 512) return;
  float b;
  if (c < 256) b = bih[c] + bhh[c];
  else if (c < 384) b = bih[c];
  else b = bhh[c - 128];
  bias_big[c] = b;
  for (int k = 0; k < NTYPES; ++k) {
    float s = 0.f;
    if (c < 384) {
      const float* wi = Wih + (size_t)c * DD;
      const float* bl = blin + (size_t)k * DD;
      for (int o = 0; o < DD; ++o) s += wi[o] * bl[o];
    }
    cb4[k * 512 + c] = s;
  }
}

// ---------- step kernel v4: counted-vmcnt double-buffer (T4), fixed swizzle ----------
// 64 rows x 256 cols, 4 waves. Per iter: STAGE(it+1) -> vmcnt(n1) -> s_barrier ->
// compute(it) -> s_barrier. No vmcnt(0) drain in the loop; batch(it+1) stays in flight.
// Swizzle f(r) = (r>>1)&3 on both source and read: 2-way banks (free).
__global__ __launch_bounds__(256) void k_gru7(
    const unsigned short* __restrict__ A3hi, const unsigned short* __restrict__ A3lo,
    const unsigned short* __restrict__ Hhi, const unsigned short* __restrict__ Hlo,
    const unsigned short* __restrict__ WbH, const unsigned short* __restrict__ WbL,
    const float* __restrict__ bias_big, const float* __restrict__ cb4,
    const int* __restrict__ deg4,
    unsigned short* __restrict__ Ohi, unsigned short* __restrict__ Olo,
    int nbase, int cc) {
  __shared__ unsigned short ldsX[2 * 4096];    // per buf: XH(2048) | XL(2048)
  __shared__ unsigned short ldsW[2 * 16384];   // per buf: WH(8192) | WL(8192)
  int tid = threadIdx.x;
  int wc = tid >> 6, lane = tid & 63;
  int lr = lane & 15, lk = lane >> 4;
  int rowbase = blockIdx.y * 64;
  int ytile = blockIdx.x;
  int wtb = ytile * 256;                       // permuted Wbig row base
  f32x4 acc[4][4];                             // [mm][gate]
  #pragma unroll
  for (int mm = 0; mm < 4; ++mm)
    #pragma unroll
    for (int g = 0; g < 4; ++g) acc[mm][g] = (f32x4){0.f, 0.f, 0.f, 0.f};

  int srow = tid >> 2, sc0 = tid & 3;
  int xcs = sc0 ^ ((srow >> 1) & 3);           // XOR pre-swizzled source chunk (f(r)=(r>>1)&3)
  int wwb = (tid & ~63) * 8;                   // wave-uniform LDS base offset (shorts)

  // stage tile k0 into buffer buf: X = 2 gloads/thread, W = 8 (or 0 for skip wave)
  auto STAGE = [&](int k0, int buf) {
    {
      const unsigned short *xsH, *xsL;
      if (k0 < 512) {
        size_t off = (size_t)(rowbase + srow) * 512 + k0 + xcs * 8;
        xsH = A3hi + off; xsL = A3lo + off;
      } else {
        size_t off = (size_t)(nbase + rowbase + srow) * DD + (k0 - 512) + xcs * 8;
        xsH = Hhi + off; xsL = Hlo + off;
      }
      unsigned short* xdst = ldsX + buf * 4096 + wwb;
      gload16(xsH, xdst);
      gload16(xsL, xdst + 2048);
    }
    int skipgrp = (k0 < 512) ? 3 : 2;
    if (wc != skipgrp) {
      #pragma unroll
      for (int i = 0; i < 4; ++i) {
        int wrow = i * 64 + srow;
        int wcs = sc0 ^ ((wrow >> 1) & 3);
        size_t woff = (size_t)(wtb + wrow) * 640 + k0 + wcs * 8;
        unsigned short* wdst = ldsW + buf * 16384 + i * 2048 + wwb;
        gload16(WbH + woff, wdst);
        gload16(WbL + woff, wdst + 8192);
      }
    }
  };

  STAGE(0, 0);
  for (int it = 0; it < 20; ++it) {
    int k0 = it * 32;
    int buf = it & 1;
    if (it + 1 < 20) {
      int nk0 = k0 + 32;
      STAGE(nk0, buf ^ 1);                     // issue next batch (stays in flight)
      int skipn = (nk0 < 512) ? 3 : 2;
      // in-order vmem retirement: outstanding<=n1 => batch(it) fully landed
      if (wc == skipn) asm volatile("s_waitcnt vmcnt(2)" ::: "memory");
      else             asm volatile("s_waitcnt vmcnt(10)" ::: "memory");
    } else {
      asm volatile("s_waitcnt vmcnt(0)" ::: "memory");
    }
    __builtin_amdgcn_sched_barrier(0);
    __builtin_amdgcn_s_barrier();              // all waves' batch(it) landed
    __builtin_amdgcn_sched_barrier(0);

    int nnSkip = (k0 < 512) ? 3 : 2;           // hn zero on A3-range, gn zero on H-range
    const unsigned short* bx = ldsX + buf * 4096;
    const unsigned short* bw = ldsW + buf * 16384;
    short8v xh[4], xl[4];
    #pragma unroll
    for (int mm = 0; mm < 4; ++mm) {
      int r = mm * 16 + lr;
      int a = r * 32 + ((lk ^ ((r >> 1) & 3)) << 3);
      xh[mm] = *(const short8v*)(bx + a);
      xl[mm] = *(const short8v*)(bx + 2048 + a);
    }
    #pragma unroll
    for (int nn = 0; nn < 4; ++nn) {
      if (nn == nnSkip) continue;
      int rw = wc * 64 + nn * 16 + lr;
      int a = rw * 32 + ((lk ^ ((rw >> 1) & 3)) << 3);
      short8v wh = *(const short8v*)(bw + a);
      short8v wl = *(const short8v*)(bw + 8192 + a);
      #pragma unroll
      for (int mm = 0; mm < 4; ++mm) {
        acc[mm][nn] = __builtin_amdgcn_mfma_f32_16x16x32_bf16(xh[mm], wh, acc[mm][nn], 0, 0, 0);
        acc[mm][nn] = __builtin_amdgcn_mfma_f32_16x16x32_bf16(xh[mm], wl, acc[mm][nn], 0, 0, 0);
        acc[mm][nn] = __builtin_amdgcn_mfma_f32_16x16x32_bf16(xl[mm], wh, acc[mm][nn], 0, 0, 0);
      }
    }
    __builtin_amdgcn_sched_barrier(0);
    __builtin_amdgcn_s_barrier();              // reads of buf done before next overwrite
  }

  // epilogue: thread owns d = ytile*64 + wc*16 + lr, gates nn=0..3
  int d = ytile * 64 + wc * 16 + lr;
  float bsr = bias_big[d], bsz = bias_big[128 + d];
  float bgn = bias_big[256 + d], bhn = bias_big[384 + d];
  float cbr[4], cbz[4], cbn[4];
  #pragma unroll
  for (int k = 0; k < 4; ++k) {
    cbr[k] = cb4[k * 512 + d];
    cbz[k] = cb4[k * 512 + 128 + d];
    cbn[k] = cb4[k * 512 + 256 + d];
  }
  #pragma unroll
  for (int mm = 0; mm < 4; ++mm) {
    #pragma unroll
    for (int j = 0; j < 4; ++j) {
      int row = rowbase + mm * 16 + lk * 4 + j;
      if (row < cc) {
        int4 dg = *(const int4*)(deg4 + (size_t)row * 4);
        float s_r = acc[mm][0][j] + bsr + dg.x * cbr[0] + dg.y * cbr[1] + dg.z * cbr[2] + dg.w * cbr[3];
        float s_z = acc[mm][1][j] + bsz + dg.x * cbz[0] + dg.y * cbz[1] + dg.z * cbz[2] + dg.w * cbz[3];
        float g_n = acc[mm][2][j] + bgn + dg.x * cbn[0] + dg.y * cbn[1] + dg.z * cbn[2] + dg.w * cbn[3];
        float h_n = acc[mm][3][j] + bhn;
        float r = 1.f / (1.f + expf(-s_r));
        float z = 1.f / (1.f + expf(-s_z));
        float nt = tanhf(g_n + r * h_n);
        size_t gidx = (size_t)(nbase + row) * DD + d;
        float hv = (1.f - z) * nt + z * rec2(Hhi, Hlo, gidx);
        unsigned short uh, ul; split2(hv, uh, ul);
        Ohi[gidx] = uh; Olo[gidx] = ul;
      }
    }
  }
}

// ---------- readout ----------
__global__ void k_gate(const unsigned short* __restrict__ hhi,
    const unsigned short* __restrict__ hlo, const float* __restrict__ ann,
    const float* __restrict__ gw, const float* __restrict__ gb,
    float* __restrict__ gate, int n) {
  int gt = blockIdx.x * blockDim.x + threadIdx.x;
  int wv = gt >> 6;
  int lane = threadIdx.x & 63;
  if (wv >= n) return;
  float p = rec2(hhi, hlo, (size_t)wv * DD + lane) * gw[lane]
          + rec2(hhi, hlo, (size_t)wv * DD + 64 + lane) * gw[64 + lane]
          + ann[(size_t)wv * ANND + lane] * gw[128 + lane];
  for (int off = 32; off; off >>= 1) p += __shfl_down(p, off);
  if (lane == 0) gate[wv] = p + gb[0];
}

// sorted node2graph -> segment bounds via boundary detection (no atomics)
__global__ void k_bounds(const int* __restrict__ n2g, int* __restrict__ startg,
    int* __restrict__ endg, int n) {
  int i = blockIdx.x * blockDim.x + threadIdx.x;
  if (i >= n) return;
  int g = n2g[i];
  if (i == 0 || n2g[i - 1] != g) startg[g] = i;
  if (i == n - 1 || n2g[i + 1] != g) endg[g] = i + 1;
}

// per-graph softmax max + 1/denominator
__global__ __launch_bounds__(256) void k_mden(const float* __restrict__ gate,
    const int* __restrict__ startg, const int* __restrict__ endg,
    float* __restrict__ mg, float* __restrict__ invg) {
  __shared__ float red[256];
  int g = blockIdx.x;
  int s = startg[g], e = endg[g];
  int tid = threadIdx.x;
  float m = -1e30f;
  for (int i = s + tid; i < e; i += 256) m = fmaxf(m, gate[i]);
  red[tid] = m; __syncthreads();
  for (int off = 128; off; off >>= 1) {
    if (tid < off) red[tid] = fmaxf(red[tid], red[tid + off]);
    __syncthreads();
  }
  m = red[0];
  __syncthreads();
  float sum = 0.f;
  for (int i = s + tid; i < e; i += 256) sum += expf(gate[i] - m);
  red[tid] = sum; __syncthreads();
  for (int off = 128; off; off >>= 1) {
    if (tid < off) red[tid] += red[tid + off];
    __syncthreads();
  }
  if (tid == 0) { mg[g] = m; invg[g] = (s < e) ? 1.f / red[0] : 0.f; }
}

// weighted readout; grid (B, 2): y=0 h-dims (packed uint pairs), y=1 ann-dims
__global__ __launch_bounds__(256) void k_pool2(const float* __restrict__ gate,
    const unsigned* __restrict__ hhiU, const unsigned* __restrict__ hloU,
    const float* __restrict__ ann, const int* __restrict__ startg,
    const int* __restrict__ endg, const float* __restrict__ mg,
    const float* __restrict__ invg, float* __restrict__ readout) {
  __shared__ float redx[256], redy[256];
  int g = blockIdx.x;
  int s = startg[g], e = endg[g];
  int nl = threadIdx.x >> 6, lane = threadIdx.x & 63;
  float m = mg[g], inv = invg[g];
  if (blockIdx.y == 0) {
    float ax = 0.f, ay = 0.f;
    for (int i = s + nl; i < e; i += 4) {
      float al = expf(gate[i] - m) * inv;
      unsigned uh = hhiU[(size_t)i * 64 + lane];
      unsigned ul = hloU[(size_t)i * 64 + lane];
      ax += al * (lo16f(uh) + lo16f(ul));
      ay += al * (hi16f(uh) + hi16f(ul));
    }
    redx[threadIdx.x] = ax; redy[threadIdx.x] = ay;
    __syncthreads();
    if (nl == 0) {
      float sx = redx[lane] + redx[64 + lane] + redx[128 + lane] + redx[192 + lane];
      float sy = redy[lane] + redy[64 + lane] + redy[128 + lane] + redy[192 + lane];
      readout[g * (DD + ANND) + 2 * lane] = sx;
      readout[g * (DD + ANND) + 2 * lane + 1] = sy;
    }
  } else {
    float acc = 0.f;
    for (int i = s + nl; i < e; i += 4) {
      float al = expf(gate[i] - m) * inv;
      acc += al * ann[(size_t)i * ANND + lane];
    }
    redx[threadIdx.x] = acc;
    __syncthreads();
    if (nl == 0)
      readout[g * (DD + ANND) + DD + lane] =
          redx[lane] + redx[64 + lane] + redx[128 + lane] + redx[192 + lane];
  }
}

__global__ void k_logits(const float* __restrict__ readout, const float* __restrict__ ow,
    const float* __restrict__ ob, const int* __restrict__ labels,
    float* __restrict__ out, int B) {
  __shared__ float lsum[64];
  int g = threadIdx.x;
  float loss_c = 0.f;
  if (g < B) {
    float lg[NCLS];
    float mx = -1e30f;
    int best = 0;
    for (int c = 0; c < NCLS; ++c) {
      float acc = ob[c];
      const float* r = readout + g * (DD + ANND);
      const float* w = ow + c * (DD + ANND);
      for (int d = 0; d < DD + ANND; ++d) acc += r[d] * w[d];
      lg[c] = acc;
      if (acc > mx) { mx = acc; best = c; }
    }
    float se = 0.f;
    for (int c = 0; c < NCLS; ++c) se += expf(lg[c] - mx);
    float lse = mx + logf(se);
    loss_c = -(lg[labels[g]] - lse);
    out[1 + g] = (float)best;
  }
  lsum[threadIdx.x] = loss_c;
  __syncthreads();
  for (int off = 32; off; off >>= 1) {
    if (threadIdx.x < off) lsum[threadIdx.x] += lsum[threadIdx.x + off];
    __syncthreads();
  }
  if (threadIdx.x == 0) out[0] = lsum[0] / (float)B;
}

extern "C" void kernel_launch(void* const* d_in, const int* in_sizes, int n_in,
                              void* d_out, int out_size, void* d_ws, size_t ws_size,
                              hipStream_t stream) {
  const float* annotation = (const float*)d_in[0];
  const int*   src        = (const int*)d_in[1];
  const int*   dst        = (const int*)d_in[2];
  const int*   et         = (const int*)d_in[3];
  const int*   n2g        = (const int*)d_in[4];
  const int*   labels     = (const int*)d_in[5];
  const float* W_lin      = (const float*)d_in[6];
  const float* b_lin      = (const float*)d_in[7];
  const float* W_ih       = (const float*)d_in[8];
  const float* W_hh       = (const float*)d_in[9];
  const float* b_ih       = (const float*)d_in[10];
  const float* b_hh       = (const float*)d_in[11];
  const float* gate_w     = (const float*)d_in[12];
  const float* gate_b     = (const float*)d_in[13];
  const float* out_w      = (const float*)d_in[14];
  const float* out_b      = (const float*)d_in[15];

  int N = in_sizes[0] / ANND;
  int E = in_sizes[1];
  int B = in_sizes[5];
  int Np = (N + 127) & ~127;

  // ---- workspace budget ----
  auto rup = [](size_t b) { return (b + 255) & ~(size_t)255; };
  size_t fixed = 0;
  fixed += 4 * rup((size_t)Np * DD * 2);           // h ping-pong planes
  fixed += rup((size_t)N * 4);                     // gate
  fixed += rup((size_t)B * (DD + ANND) * 4);       // readout
  fixed += 4 * rup((size_t)B * 4);                 // startg, endg, mg, invg
  fixed += rup((size_t)(N + 1) * 4);               // base
  fixed += rup((size_t)N * 4);                     // cursor
  fixed += rup((size_t)N * 16);                    // deg4
  fixed += rup((size_t)E * 4);                     // cpack
  fixed += rup(384 * 512 * 4);                     // VW
  fixed += 2 * rup(512 * 640 * 2);                 // WbH, WbL
  fixed += rup(512 * 4) + rup(4 * 512 * 4);        // bias_big, cb4
  size_t slack = 1 << 20;
  size_t avail = (ws_size > fixed + slack) ? ws_size - fixed - slack : 0;
  long long ch = (long long)(avail / 2048);        // A3 planes per node
  int CH = (int)((ch / 128) * 128);
  if (CH < 128) CH = 128;
  if (CH > Np) CH = Np;

  char* wsP = (char*)d_ws;
  auto alloc = [&](size_t bytes) -> void* {
    void* p = (void*)wsP;
    wsP += (bytes + 255) & ~(size_t)255;
    return p;
  };
  unsigned short* hP_hi[2], *hP_lo[2];
  hP_hi[0] = (unsigned short*)alloc((size_t)Np * DD * 2);
  hP_lo[0] = (unsigned short*)alloc((size_t)Np * DD * 2);
  hP_hi[1] = (unsigned short*)alloc((size_t)Np * DD * 2);
  hP_lo[1] = (unsigned short*)alloc((size_t)Np * DD * 2);
  float* gate = (float*)alloc((size_t)N * 4);
  float* readout = (float*)alloc((size_t)B * (DD + ANND) * 4);
  int* startg = (int*)alloc((size_t)B * 4);
  int* endg   = (int*)alloc((size_t)B * 4);
  float* mg   = (float*)alloc((size_t)B * 4);
  float* invg = (float*)alloc((size_t)B * 4);
  int* base   = (int*)alloc((size_t)(N + 1) * 4);
  int* cursor = (int*)alloc((size_t)N * 4);
  int* deg4   = (int*)alloc((size_t)N * 16);
  int* cpack  = (int*)alloc((size_t)E * 4);
  float* VW   = (float*)alloc(384 * 512 * 4);
  unsigned short* WbH = (unsigned short*)alloc(512 * 640 * 2);
  unsigned short* WbL = (unsigned short*)alloc(512 * 640 * 2);
  float* bias_big = (float*)alloc(512 * 4);
  float* cb4  = (float*)alloc(4 * 512 * 4);
  unsigned short* A3hi = (unsigned short*)alloc((size_t)CH * 512 * 2);
  unsigned short* A3lo = (unsigned short*)alloc((size_t)CH * 512 * 2);

  // init + CSR + fused-weight prep (once per launch)
  k_init<<<(Np * DD + 255) / 256, 256, 0, stream>>>(annotation, hP_hi[0], hP_lo[0], N, Np);
  hipMemsetAsync(cursor, 0, (size_t)N * 4, stream);
  hipMemsetAsync(deg4, 0, (size_t)N * 16, stream);
  hipMemsetAsync(startg, 0x7f, (size_t)B * 4, stream);
  hipMemsetAsync(endg, 0, (size_t)B * 4, stream);
  k_deg4<<<(E + 255) / 256, 256, 0, stream>>>(dst, et, deg4, E);
  k_scan<<<1, 1024, 0, stream>>>(deg4, base, N);
  k_place<<<(E + 255) / 256, 256, 0, stream>>>(src, dst, et, base, cursor, cpack, E);
  k_bounds<<<(N + 255) / 256, 256, 0, stream>>>(n2g, startg, endg, N);
  k_fusew<<<(384 * 512 + 255) / 256, 256, 0, stream>>>(W_ih, W_lin, VW);
  k_wbig<<<(512 * 640 + 255) / 256, 256, 0, stream>>>(VW, W_hh, WbH, WbL);
  k_fuseb<<<2, 256, 0, stream>>>(W_ih, b_ih, b_hh, b_lin, bias_big, cb4);

  int cur = 0;
  for (int s = 0; s < NSTEPS; ++s) {
    int nxt = cur ^ 1;
    for (int nbase = 0; nbase < N; nbase += CH) {
      int cc = min(CH, N - nbase);
      int cgrid = (cc + 63) / 64;
      k_aggh<<<(cc + 3) / 4, 256, 0, stream>>>(
          (const unsigned*)hP_hi[cur], (const unsigned*)hP_lo[cur], base, cpack,
          (unsigned*)A3hi, (unsigned*)A3lo, nbase, cc);
      k_gru7<<<dim3(2, cgrid), 256, 0, stream>>>(A3hi, A3lo,
          hP_hi[cur], hP_lo[cur], WbH, WbL, bias_big, cb4,
          deg4 + (size_t)nbase * 4, hP_hi[nxt], hP_lo[nxt], nbase, cc);
    }
    cur ^= 1;
  }

  k_gate<<<(N * 64 + 255) / 256, 256, 0, stream>>>(
      hP_hi[cur], hP_lo[cur], annotation, gate_w, gate_b, gate, N);
  k_mden<<<B, 256, 0, stream>>>(gate, startg, endg, mg, invg);
  k_pool2<<<dim3(B, 2), 256, 0, stream>>>(gate, (const unsigned*)hP_hi[cur],
      (const unsigned*)hP_lo[cur], annotation, startg, endg, mg, invg, readout);
  k_logits<<<1, 64, 0, stream>>>(readout, out_w, out_b, labels, (float*)d_out, B);
}

// Round 14
// 1163.753 us; speedup vs baseline: 1.0849x; 1.0773x over previous
//
#include <hip/hip_runtime.h>
#include <math.h>

#define DD 128      // hidden dim
#define ANND 64     // annotation dim
#define NSTEPS 5
#define NTYPES 4
#define NCLS 10

typedef __attribute__((ext_vector_type(8))) short short8v;  // 8 bf16
typedef __attribute__((ext_vector_type(4))) float f32x4;

// split fp32 into hi+lo bf16 (RNE both)
__device__ __forceinline__ void split2(float x, unsigned short& hi, unsigned short& lo) {
  unsigned u = __float_as_uint(x);
  unsigned hb = (u + 0x7FFFu + ((u >> 16) & 1u)) >> 16;
  hi = (unsigned short)hb;
  float r = x - __uint_as_float(hb << 16);
  unsigned v = __float_as_uint(r);
  lo = (unsigned short)((v + 0x7FFFu + ((v >> 16) & 1u)) >> 16);
}

__device__ __forceinline__ float bf2f(unsigned short u) {
  return __uint_as_float(((unsigned)u) << 16);
}
__device__ __forceinline__ float rec2(const unsigned short* hi, const unsigned short* lo, size_t i) {
  return bf2f(hi[i]) + bf2f(lo[i]);
}
__device__ __forceinline__ float lo16f(unsigned u) { return __uint_as_float(u << 16); }
__device__ __forceinline__ float hi16f(unsigned u) { return __uint_as_float(u & 0xffff0000u); }

// async global->LDS, 16B per lane (dest = wave-uniform base + lane*16)
__device__ __forceinline__ void gload16(const unsigned short* g, unsigned short* l) {
  __builtin_amdgcn_global_load_lds(
      (const __attribute__((address_space(1))) unsigned int*)(const void*)g,
      (__attribute__((address_space(3))) unsigned int*)(void*)l, 16, 0, 0);
}

// h = [ann | 0] as split planes; zero-fill padded rows [n, npad)
__global__ void k_init(const float* __restrict__ ann,
    unsigned short* __restrict__ hhi, unsigned short* __restrict__ hlo, int n, int npad) {
  int idx = blockIdx.x * blockDim.x + threadIdx.x;
  if (idx >= npad * DD) return;
  int node = idx >> 7, d = idx & 127;
  float v = (node < n && d < ANND) ? ann[node * ANND + d] : 0.0f;
  unsigned short hi, lo; split2(v, hi, lo);
  hhi[idx] = hi; hlo[idx] = lo;
}

// ---------- CSR build (by dst), once per launch ----------
__global__ void k_deg4(const int* __restrict__ dst, const int* __restrict__ et,
    int* __restrict__ deg4, int e) {
  int i = blockIdx.x * blockDim.x + threadIdx.x;
  if (i < e) atomicAdd(&deg4[dst[i] * 4 + et[i]], 1);
}

__global__ __launch_bounds__(1024) void k_scan(const int* __restrict__ deg4,
    int* __restrict__ base, int n) {
  __shared__ int part[1024];
  int t = threadIdx.x;
  int chunk = (n + 1023) >> 10;
  int s = t * chunk, e = min(n, s + chunk);
  int sum = 0;
  for (int i = s; i < e; ++i) {
    const int4 d4 = *(const int4*)(deg4 + (size_t)i * 4);
    sum += d4.x + d4.y + d4.z + d4.w;
  }
  part[t] = sum;
  __syncthreads();
  int own = sum;
  for (int off = 1; off < 1024; off <<= 1) {
    int v = (t >= off) ? part[t - off] : 0;
    __syncthreads();
    part[t] += v;
    __syncthreads();
  }
  int run = part[t] - own;
  for (int i = s; i < e; ++i) {
    base[i] = run;
    const int4 d4 = *(const int4*)(deg4 + (size_t)i * 4);
    run += d4.x + d4.y + d4.z + d4.w;
  }
  if (s < n && e == n) base[n] = run;
}

__global__ void k_place(const int* __restrict__ src, const int* __restrict__ dst,
    const int* __restrict__ et, const int* __restrict__ base, int* __restrict__ cursor,
    int* __restrict__ cpack, int e) {
  int i = blockIdx.x * blockDim.x + threadIdx.x;
  if (i >= e) return;
  int d = dst[i];
  int pos = base[d] + atomicAdd(&cursor[d], 1);
  cpack[pos] = src[i] | (et[i] << 18);
}

// ---------- per-type neighbor sums: one WAVE per node, shfl-broadcast indices ----------
__global__ void k_aggh(const unsigned* __restrict__ hhiU, const unsigned* __restrict__ hloU,
    const int* __restrict__ base, const int* __restrict__ cpack,
    unsigned* __restrict__ A3hiU, unsigned* __restrict__ A3loU, int nbase, int cc) {
  int w = threadIdx.x >> 6;
  int lane = threadIdx.x & 63;
  int local = blockIdx.x * 4 + w;
  if (local >= cc) return;
  int node = nbase + local;
  int s = base[node], e = base[node + 1];
  float a0x = 0.f, a0y = 0.f, a1x = 0.f, a1y = 0.f;
  float a2x = 0.f, a2y = 0.f, a3x = 0.f, a3y = 0.f;
  for (int t0 = s; t0 < e; t0 += 64) {
    int cnt = min(64, e - t0);
    int mypk = (t0 + lane < e) ? cpack[t0 + lane] : 0;
    int i = 0;
    for (; i + 4 <= cnt; i += 4) {
      int pk0 = __shfl(mypk, i), pk1 = __shfl(mypk, i + 1);
      int pk2 = __shfl(mypk, i + 2), pk3 = __shfl(mypk, i + 3);
      unsigned uh0 = hhiU[(size_t)(pk0 & 0x3ffff) * 64 + lane];
      unsigned ul0 = hloU[(size_t)(pk0 & 0x3ffff) * 64 + lane];
      unsigned uh1 = hhiU[(size_t)(pk1 & 0x3ffff) * 64 + lane];
      unsigned ul1 = hloU[(size_t)(pk1 & 0x3ffff) * 64 + lane];
      unsigned uh2 = hhiU[(size_t)(pk2 & 0x3ffff) * 64 + lane];
      unsigned ul2 = hloU[(size_t)(pk2 & 0x3ffff) * 64 + lane];
      unsigned uh3 = hhiU[(size_t)(pk3 & 0x3ffff) * 64 + lane];
      unsigned ul3 = hloU[(size_t)(pk3 & 0x3ffff) * 64 + lane];
      float v0x = lo16f(uh0) + lo16f(ul0), v0y = hi16f(uh0) + hi16f(ul0);
      float v1x = lo16f(uh1) + lo16f(ul1), v1y = hi16f(uh1) + hi16f(ul1);
      float v2x = lo16f(uh2) + lo16f(ul2), v2y = hi16f(uh2) + hi16f(ul2);
      float v3x = lo16f(uh3) + lo16f(ul3), v3y = hi16f(uh3) + hi16f(ul3);
      int t;
      t = pk0 >> 18;
      if (t == 0) { a0x += v0x; a0y += v0y; } else if (t == 1) { a1x += v0x; a1y += v0y; }
      else if (t == 2) { a2x += v0x; a2y += v0y; } else { a3x += v0x; a3y += v0y; }
      t = pk1 >> 18;
      if (t == 0) { a0x += v1x; a0y += v1y; } else if (t == 1) { a1x += v1x; a1y += v1y; }
      else if (t == 2) { a2x += v1x; a2y += v1y; } else { a3x += v1x; a3y += v1y; }
      t = pk2 >> 18;
      if (t == 0) { a0x += v2x; a0y += v2y; } else if (t == 1) { a1x += v2x; a1y += v2y; }
      else if (t == 2) { a2x += v2x; a2y += v2y; } else { a3x += v2x; a3y += v2y; }
      t = pk3 >> 18;
      if (t == 0) { a0x += v3x; a0y += v3y; } else if (t == 1) { a1x += v3x; a1y += v3y; }
      else if (t == 2) { a2x += v3x; a2y += v3y; } else { a3x += v3x; a3y += v3y; }
    }
    for (; i < cnt; ++i) {
      int pk = __shfl(mypk, i);
      unsigned uh = hhiU[(size_t)(pk & 0x3ffff) * 64 + lane];
      unsigned ul = hloU[(size_t)(pk & 0x3ffff) * 64 + lane];
      float vx = lo16f(uh) + lo16f(ul), vy = hi16f(uh) + hi16f(ul);
      int t = pk >> 18;
      if (t == 0) { a0x += vx; a0y += vy; } else if (t == 1) { a1x += vx; a1y += vy; }
      else if (t == 2) { a2x += vx; a2y += vy; } else { a3x += vx; a3y += vy; }
    }
  }
  size_t bu = (size_t)local * 256 + lane;
  unsigned short h0, l0, h1, l1;
  split2(a0x, h0, l0); split2(a0y, h1, l1);
  A3hiU[bu] = (unsigned)h0 | ((unsigned)h1 << 16);
  A3loU[bu] = (unsigned)l0 | ((unsigned)l1 << 16);
  split2(a1x, h0, l0); split2(a1y, h1, l1);
  A3hiU[bu + 64] = (unsigned)h0 | ((unsigned)h1 << 16);
  A3loU[bu + 64] = (unsigned)l0 | ((unsigned)l1 << 16);
  split2(a2x, h0, l0); split2(a2y, h1, l1);
  A3hiU[bu + 128] = (unsigned)h0 | ((unsigned)h1 << 16);
  A3loU[bu + 128] = (unsigned)l0 | ((unsigned)l1 << 16);
  split2(a3x, h0, l0); split2(a3y, h1, l1);
  A3hiU[bu + 192] = (unsigned)h0 | ((unsigned)h1 << 16);
  A3loU[bu + 192] = (unsigned)l0 | ((unsigned)l1 << 16);
}

// ---------- fused-weight prep (once per launch) ----------
// VW[c][k*128+d] = sum_o W_ih[c][o] * W_lin[k][o][d]   (384 x 512, fp32)
__global__ void k_fusew(const float* __restrict__ Wih, const float* __restrict__ Wlin,
    float* __restrict__ VW) {
  int idx = blockIdx.x * blockDim.x + threadIdx.x;
  if (idx >= 384 * 512) return;
  int c = idx >> 9, kd = idx & 511;
  int k = kd >> 7, d = kd & 127;
  const float* wi = Wih + (size_t)c * DD;
  const float* wl = Wlin + (size_t)k * DD * DD + d;
  float s = 0.f;
  for (int o = 0; o < DD; ++o) s += wi[o] * wl[(size_t)o * DD];
  VW[idx] = s;
}

// Wbig[512][640] with PERMUTED rows: c_new = (d>>5)*128 + ((d>>4)&1)*64 + g*16 + (d&15)
// original row c = g*128+d; value: gates over K = [A3(512) | H(128)], gn zero on H, hn zero on A3
__global__ void k_wbig(const float* __restrict__ VW, const float* __restrict__ Whh,
    unsigned short* __restrict__ WbH, unsigned short* __restrict__ WbL) {
  int idx = blockIdx.x * blockDim.x + threadIdx.x;
  if (idx >= 512 * 640) return;
  int c = idx / 640, k = idx % 640;
  float v;
  if (c < 256)      v = (k < 512) ? VW[(size_t)c * 512 + k] : Whh[(size_t)c * DD + (k - 512)];
  else if (c < 384) v = (k < 512) ? VW[(size_t)c * 512 + k] : 0.f;
  else              v = (k < 512) ? 0.f : Whh[(size_t)(c - 128) * DD + (k - 512)];
  int g = c >> 7, d = c & 127;
  int cn = ((d >> 5) << 7) + (((d >> 4) & 1) << 6) + (g << 4) + (d & 15);
  unsigned short h, l; split2(v, h, l);
  WbH[(size_t)cn * 640 + k] = h;
  WbL[(size_t)cn * 640 + k] = l;
}

// bias_big[512] (layout g*128+d) and cb4[4][512]
__global__ void k_fuseb(const float* __restrict__ Wih, const float* __restrict__ bih,
    const float* __restrict__ bhh, const float* __restrict__ blin,
    float* __restrict__ bias_big, float* __restrict__ cb4) {
  int c = blockIdx.x * blockDim.x + threadIdx.x;
  if (c >= 512) return;
  float b;
  if (c < 256) b = bih[c] + bhh[c];
  else if (c < 384) b = bih[c];
  else b = bhh[c - 128];
  bias_big[c] = b;
  for (int k = 0; k < NTYPES; ++k) {
    float s = 0.f;
    if (c < 384) {
      const float* wi = Wih + (size_t)c * DD;
      const float* bl = blin + (size_t)k * DD;
      for (int o = 0; o < DD; ++o) s += wi[o] * bl[o];
    }
    cb4[k * 512 + c] = s;
  }
}

// ---------- step kernel v5: minimum-LDS (32 KiB -> 5 blocks/CU), compact W ----------
// 64 rows x 256 cols, 4 waves, single-buffered, simple 2-barrier loop (R11 structure).
// Only the 3 live gates are staged (192 compact W rows); conflict-free swizzle f(r)=(r>>1)&3.
__global__ __launch_bounds__(256) void k_gru8(
    const unsigned short* __restrict__ A3hi, const unsigned short* __restrict__ A3lo,
    const unsigned short* __restrict__ Hhi, const unsigned short* __restrict__ Hlo,
    const unsigned short* __restrict__ WbH, const unsigned short* __restrict__ WbL,
    const float* __restrict__ bias_big, const float* __restrict__ cb4,
    const int* __restrict__ deg4,
    unsigned short* __restrict__ Ohi, unsigned short* __restrict__ Olo,
    int nbase, int cc) {
  __shared__ unsigned short ldsX[4096];     // XH(2048) | XL(2048)   8 KiB
  __shared__ unsigned short ldsW[12288];    // WH(6144) | WL(6144)  24 KiB (192 compact rows)
  int tid = threadIdx.x;
  int wc = tid >> 6, lane = tid & 63;
  int lr = lane & 15, lk = lane >> 4;
  int rowbase = blockIdx.y * 64;
  int ytile = blockIdx.x;
  int wtb = ytile * 256;                    // permuted Wbig row base
  f32x4 acc[4][4];                          // [mm][gate]
  #pragma unroll
  for (int mm = 0; mm < 4; ++mm)
    #pragma unroll
    for (int g = 0; g < 4; ++g) acc[mm][g] = (f32x4){0.f, 0.f, 0.f, 0.f};

  int srow = tid >> 2, sc0 = tid & 3;
  int xcs = sc0 ^ ((srow >> 1) & 3);        // conflict-free source swizzle
  int wwb = (tid & ~63) * 8;                // wave-uniform LDS base offset (shorts)

  for (int it = 0; it < 20; ++it) {
    int k0 = it * 32;
    __syncthreads();                        // previous compute done before overwrite
    {  // stage X: 64 rows x 32 shorts x 2 planes
      const unsigned short *xsH, *xsL;
      if (k0 < 512) {
        size_t off = (size_t)(rowbase + srow) * 512 + k0 + xcs * 8;
        xsH = A3hi + off; xsL = A3lo + off;
      } else {
        size_t off = (size_t)(nbase + rowbase + srow) * DD + (k0 - 512) + xcs * 8;
        xsH = Hhi + off; xsL = Hlo + off;
      }
      gload16(xsH, ldsX + wwb);
      gload16(xsL, ldsX + 2048 + wwb);
    }
    int skip = (k0 < 512) ? 3 : 2;
    #pragma unroll
    for (int i2 = 0; i2 < 3; ++i2) {        // stage compact W: 192 rows x 32 shorts x 2 planes
      int rc = i2 * 64 + srow;              // compact row 0..191
      int grp = rc / 48, rem = rc - grp * 48;
      int s = rem >> 4, w16 = rem & 15;
      int g = s + (s >= skip ? 1 : 0);      // slot -> live gate
      int srcrow = grp * 64 + g * 16 + w16;
      int wcs = sc0 ^ ((rc >> 1) & 3);
      size_t woff = (size_t)(wtb + srcrow) * 640 + k0 + wcs * 8;
      unsigned short* wdst = ldsW + i2 * 2048 + wwb;
      gload16(WbH + woff, wdst);
      gload16(WbL + woff, wdst + 6144);
    }
    __syncthreads();                        // drain stage (vmcnt0 at barrier)

    int nnSkip = skip;                      // hn zero on A3-range, gn zero on H-range
    short8v xh[4], xl[4];
    #pragma unroll
    for (int mm = 0; mm < 4; ++mm) {
      int r = mm * 16 + lr;
      int a = r * 32 + ((lk ^ ((r >> 1) & 3)) << 3);
      xh[mm] = *(const short8v*)(ldsX + a);
      xl[mm] = *(const short8v*)(ldsX + 2048 + a);
    }
    #pragma unroll
    for (int nn = 0; nn < 4; ++nn) {
      if (nn == nnSkip) continue;
      int s = nn - (nn > nnSkip ? 1 : 0);   // gate -> compact slot
      int rc = wc * 48 + s * 16 + lr;
      int a = rc * 32 + ((lk ^ ((rc >> 1) & 3)) << 3);
      short8v wh = *(const short8v*)(ldsW + a);
      short8v wl = *(const short8v*)(ldsW + 6144 + a);
      #pragma unroll
      for (int mm = 0; mm < 4; ++mm) {
        acc[mm][nn] = __builtin_amdgcn_mfma_f32_16x16x32_bf16(xh[mm], wh, acc[mm][nn], 0, 0, 0);
        acc[mm][nn] = __builtin_amdgcn_mfma_f32_16x16x32_bf16(xh[mm], wl, acc[mm][nn], 0, 0, 0);
        acc[mm][nn] = __builtin_amdgcn_mfma_f32_16x16x32_bf16(xl[mm], wh, acc[mm][nn], 0, 0, 0);
      }
    }
  }

  // epilogue: thread owns d = ytile*64 + wc*16 + lr, gates nn=0..3
  int d = ytile * 64 + wc * 16 + lr;
  float bsr = bias_big[d], bsz = bias_big[128 + d];
  float bgn = bias_big[256 + d], bhn = bias_big[384 + d];
  float cbr[4], cbz[4], cbn[4];
  #pragma unroll
  for (int k = 0; k < 4; ++k) {
    cbr[k] = cb4[k * 512 + d];
    cbz[k] = cb4[k * 512 + 128 + d];
    cbn[k] = cb4[k * 512 + 256 + d];
  }
  #pragma unroll
  for (int mm = 0; mm < 4; ++mm) {
    #pragma unroll
    for (int j = 0; j < 4; ++j) {
      int row = rowbase + mm * 16 + lk * 4 + j;
      if (row < cc) {
        int4 dg = *(const int4*)(deg4 + (size_t)row * 4);
        float s_r = acc[mm][0][j] + bsr + dg.x * cbr[0] + dg.y * cbr[1] + dg.z * cbr[2] + dg.w * cbr[3];
        float s_z = acc[mm][1][j] + bsz + dg.x * cbz[0] + dg.y * cbz[1] + dg.z * cbz[2] + dg.w * cbz[3];
        float g_n = acc[mm][2][j] + bgn + dg.x * cbn[0] + dg.y * cbn[1] + dg.z * cbn[2] + dg.w * cbn[3];
        float h_n = acc[mm][3][j] + bhn;
        float r = 1.f / (1.f + expf(-s_r));
        float z = 1.f / (1.f + expf(-s_z));
        float nt = tanhf(g_n + r * h_n);
        size_t gidx = (size_t)(nbase + row) * DD + d;
        float hv = (1.f - z) * nt + z * rec2(Hhi, Hlo, gidx);
        unsigned short uh, ul; split2(hv, uh, ul);
        Ohi[gidx] = uh; Olo[gidx] = ul;
      }
    }
  }
}

// ---------- readout ----------
__global__ void k_gate(const unsigned short* __restrict__ hhi,
    const unsigned short* __restrict__ hlo, const float* __restrict__ ann,
    const float* __restrict__ gw, const float* __restrict__ gb,
    float* __restrict__ gate, int n) {
  int gt = blockIdx.x * blockDim.x + threadIdx.x;
  int wv = gt >> 6;
  int lane = threadIdx.x & 63;
  if (wv >= n) return;
  float p = rec2(hhi, hlo, (size_t)wv * DD + lane) * gw[lane]
          + rec2(hhi, hlo, (size_t)wv * DD + 64 + lane) * gw[64 + lane]
          + ann[(size_t)wv * ANND + lane] * gw[128 + lane];
  for (int off = 32; off; off >>= 1) p += __shfl_down(p, off);
  if (lane == 0) gate[wv] = p + gb[0];
}

// sorted node2graph -> segment bounds via boundary detection (no atomics)
__global__ void k_bounds(const int* __restrict__ n2g, int* __restrict__ startg,
    int* __restrict__ endg, int n) {
  int i = blockIdx.x * blockDim.x + threadIdx.x;
  if (i >= n) return;
  int g = n2g[i];
  if (i == 0 || n2g[i - 1] != g) startg[g] = i;
  if (i == n - 1 || n2g[i + 1] != g) endg[g] = i + 1;
}

// per-graph softmax max + 1/denominator
__global__ __launch_bounds__(256) void k_mden(const float* __restrict__ gate,
    const int* __restrict__ startg, const int* __restrict__ endg,
    float* __restrict__ mg, float* __restrict__ invg) {
  __shared__ float red[256];
  int g = blockIdx.x;
  int s = startg[g], e = endg[g];
  int tid = threadIdx.x;
  float m = -1e30f;
  for (int i = s + tid; i < e; i += 256) m = fmaxf(m, gate[i]);
  red[tid] = m; __syncthreads();
  for (int off = 128; off; off >>= 1) {
    if (tid < off) red[tid] = fmaxf(red[tid], red[tid + off]);
    __syncthreads();
  }
  m = red[0];
  __syncthreads();
  float sum = 0.f;
  for (int i = s + tid; i < e; i += 256) sum += expf(gate[i] - m);
  red[tid] = sum; __syncthreads();
  for (int off = 128; off; off >>= 1) {
    if (tid < off) red[tid] += red[tid + off];
    __syncthreads();
  }
  if (tid == 0) { mg[g] = m; invg[g] = (s < e) ? 1.f / red[0] : 0.f; }
}

// weighted readout; grid (B, 2): y=0 h-dims (packed uint pairs), y=1 ann-dims
__global__ __launch_bounds__(256) void k_pool2(const float* __restrict__ gate,
    const unsigned* __restrict__ hhiU, const unsigned* __restrict__ hloU,
    const float* __restrict__ ann, const int* __restrict__ startg,
    const int* __restrict__ endg, const float* __restrict__ mg,
    const float* __restrict__ invg, float* __restrict__ readout) {
  __shared__ float redx[256], redy[256];
  int g = blockIdx.x;
  int s = startg[g], e = endg[g];
  int nl = threadIdx.x >> 6, lane = threadIdx.x & 63;
  float m = mg[g], inv = invg[g];
  if (blockIdx.y == 0) {
    float ax = 0.f, ay = 0.f;
    for (int i = s + nl; i < e; i += 4) {
      float al = expf(gate[i] - m) * inv;
      unsigned uh = hhiU[(size_t)i * 64 + lane];
      unsigned ul = hloU[(size_t)i * 64 + lane];
      ax += al * (lo16f(uh) + lo16f(ul));
      ay += al * (hi16f(uh) + hi16f(ul));
    }
    redx[threadIdx.x] = ax; redy[threadIdx.x] = ay;
    __syncthreads();
    if (nl == 0) {
      float sx = redx[lane] + redx[64 + lane] + redx[128 + lane] + redx[192 + lane];
      float sy = redy[lane] + redy[64 + lane] + redy[128 + lane] + redy[192 + lane];
      readout[g * (DD + ANND) + 2 * lane] = sx;
      readout[g * (DD + ANND) + 2 * lane + 1] = sy;
    }
  } else {
    float acc = 0.f;
    for (int i = s + nl; i < e; i += 4) {
      float al = expf(gate[i] - m) * inv;
      acc += al * ann[(size_t)i * ANND + lane];
    }
    redx[threadIdx.x] = acc;
    __syncthreads();
    if (nl == 0)
      readout[g * (DD + ANND) + DD + lane] =
          redx[lane] + redx[64 + lane] + redx[128 + lane] + redx[192 + lane];
  }
}

__global__ void k_logits(const float* __restrict__ readout, const float* __restrict__ ow,
    const float* __restrict__ ob, const int* __restrict__ labels,
    float* __restrict__ out, int B) {
  __shared__ float lsum[64];
  int g = threadIdx.x;
  float loss_c = 0.f;
  if (g < B) {
    float lg[NCLS];
    float mx = -1e30f;
    int best = 0;
    for (int c = 0; c < NCLS; ++c) {
      float acc = ob[c];
      const float* r = readout + g * (DD + ANND);
      const float* w = ow + c * (DD + ANND);
      for (int d = 0; d < DD + ANND; ++d) acc += r[d] * w[d];
      lg[c] = acc;
      if (acc > mx) { mx = acc; best = c; }
    }
    float se = 0.f;
    for (int c = 0; c < NCLS; ++c) se += expf(lg[c] - mx);
    float lse = mx + logf(se);
    loss_c = -(lg[labels[g]] - lse);
    out[1 + g] = (float)best;
  }
  lsum[threadIdx.x] = loss_c;
  __syncthreads();
  for (int off = 32; off; off >>= 1) {
    if (threadIdx.x < off) lsum[threadIdx.x] += lsum[threadIdx.x + off];
    __syncthreads();
  }
  if (threadIdx.x == 0) out[0] = lsum[0] / (float)B;
}

extern "C" void kernel_launch(void* const* d_in, const int* in_sizes, int n_in,
                              void* d_out, int out_size, void* d_ws, size_t ws_size,
                              hipStream_t stream) {
  const float* annotation = (const float*)d_in[0];
  const int*   src        = (const int*)d_in[1];
  const int*   dst        = (const int*)d_in[2];
  const int*   et         = (const int*)d_in[3];
  const int*   n2g        = (const int*)d_in[4];
  const int*   labels     = (const int*)d_in[5];
  const float* W_lin      = (const float*)d_in[6];
  const float* b_lin      = (const float*)d_in[7];
  const float* W_ih       = (const float*)d_in[8];
  const float* W_hh       = (const float*)d_in[9];
  const float* b_ih       = (const float*)d_in[10];
  const float* b_hh       = (const float*)d_in[11];
  const float* gate_w     = (const float*)d_in[12];
  const float* gate_b     = (const float*)d_in[13];
  const float* out_w      = (const float*)d_in[14];
  const float* out_b      = (const float*)d_in[15];

  int N = in_sizes[0] / ANND;
  int E = in_sizes[1];
  int B = in_sizes[5];
  int Np = (N + 127) & ~127;

  // ---- workspace budget ----
  auto rup = [](size_t b) { return (b + 255) & ~(size_t)255; };
  size_t fixed = 0;
  fixed += 4 * rup((size_t)Np * DD * 2);           // h ping-pong planes
  fixed += rup((size_t)N * 4);                     // gate
  fixed += rup((size_t)B * (DD + ANND) * 4);       // readout
  fixed += 4 * rup((size_t)B * 4);                 // startg, endg, mg, invg
  fixed += rup((size_t)(N + 1) * 4);               // base
  fixed += rup((size_t)N * 4);                     // cursor
  fixed += rup((size_t)N * 16);                    // deg4
  fixed += rup((size_t)E * 4);                     // cpack
  fixed += rup(384 * 512 * 4);                     // VW
  fixed += 2 * rup(512 * 640 * 2);                 // WbH, WbL
  fixed += rup(512 * 4) + rup(4 * 512 * 4);        // bias_big, cb4
  size_t slack = 1 << 20;
  size_t avail = (ws_size > fixed + slack) ? ws_size - fixed - slack : 0;
  long long ch = (long long)(avail / 2048);        // A3 planes per node
  int CH = (int)((ch / 128) * 128);
  if (CH < 128) CH = 128;
  if (CH > Np) CH = Np;

  char* wsP = (char*)d_ws;
  auto alloc = [&](size_t bytes) -> void* {
    void* p = (void*)wsP;
    wsP += (bytes + 255) & ~(size_t)255;
    return p;
  };
  unsigned short* hP_hi[2], *hP_lo[2];
  hP_hi[0] = (unsigned short*)alloc((size_t)Np * DD * 2);
  hP_lo[0] = (unsigned short*)alloc((size_t)Np * DD * 2);
  hP_hi[1] = (unsigned short*)alloc((size_t)Np * DD * 2);
  hP_lo[1] = (unsigned short*)alloc((size_t)Np * DD * 2);
  float* gate = (float*)alloc((size_t)N * 4);
  float* readout = (float*)alloc((size_t)B * (DD + ANND) * 4);
  int* startg = (int*)alloc((size_t)B * 4);
  int* endg   = (int*)alloc((size_t)B * 4);
  float* mg   = (float*)alloc((size_t)B * 4);
  float* invg = (float*)alloc((size_t)B * 4);
  int* base   = (int*)alloc((size_t)(N + 1) * 4);
  int* cursor = (int*)alloc((size_t)N * 4);
  int* deg4   = (int*)alloc((size_t)N * 16);
  int* cpack  = (int*)alloc((size_t)E * 4);
  float* VW   = (float*)alloc(384 * 512 * 4);
  unsigned short* WbH = (unsigned short*)alloc(512 * 640 * 2);
  unsigned short* WbL = (unsigned short*)alloc(512 * 640 * 2);
  float* bias_big = (float*)alloc(512 * 4);
  float* cb4  = (float*)alloc(4 * 512 * 4);
  unsigned short* A3hi = (unsigned short*)alloc((size_t)CH * 512 * 2);
  unsigned short* A3lo = (unsigned short*)alloc((size_t)CH * 512 * 2);

  // init + CSR + fused-weight prep (once per launch)
  k_init<<<(Np * DD + 255) / 256, 256, 0, stream>>>(annotation, hP_hi[0], hP_lo[0], N, Np);
  hipMemsetAsync(cursor, 0, (size_t)N * 4, stream);
  hipMemsetAsync(deg4, 0, (size_t)N * 16, stream);
  hipMemsetAsync(startg, 0x7f, (size_t)B * 4, stream);
  hipMemsetAsync(endg, 0, (size_t)B * 4, stream);
  k_deg4<<<(E + 255) / 256, 256, 0, stream>>>(dst, et, deg4, E);
  k_scan<<<1, 1024, 0, stream>>>(deg4, base, N);
  k_place<<<(E + 255) / 256, 256, 0, stream>>>(src, dst, et, base, cursor, cpack, E);
  k_bounds<<<(N + 255) / 256, 256, 0, stream>>>(n2g, startg, endg, N);
  k_fusew<<<(384 * 512 + 255) / 256, 256, 0, stream>>>(W_ih, W_lin, VW);
  k_wbig<<<(512 * 640 + 255) / 256, 256, 0, stream>>>(VW, W_hh, WbH, WbL);
  k_fuseb<<<2, 256, 0, stream>>>(W_ih, b_ih, b_hh, b_lin, bias_big, cb4);

  int cur = 0;
  for (int s = 0; s < NSTEPS; ++s) {
    int nxt = cur ^ 1;
    for (int nbase = 0; nbase < N; nbase += CH) {
      int cc = min(CH, N - nbase);
      int cgrid = (cc + 63) / 64;
      k_aggh<<<(cc + 3) / 4, 256, 0, stream>>>(
          (const unsigned*)hP_hi[cur], (const unsigned*)hP_lo[cur], base, cpack,
          (unsigned*)A3hi, (unsigned*)A3lo, nbase, cc);
      k_gru8<<<dim3(2, cgrid), 256, 0, stream>>>(A3hi, A3lo,
          hP_hi[cur], hP_lo[cur], WbH, WbL, bias_big, cb4,
          deg4 + (size_t)nbase * 4, hP_hi[nxt], hP_lo[nxt], nbase, cc);
    }
    cur ^= 1;
  }

  k_gate<<<(N * 64 + 255) / 256, 256, 0, stream>>>(
      hP_hi[cur], hP_lo[cur], annotation, gate_w, gate_b, gate, N);
  k_mden<<<B, 256, 0, stream>>>(gate, startg, endg, mg, invg);
  k_pool2<<<dim3(B, 2), 256, 0, stream>>>(gate, (const unsigned*)hP_hi[cur],
      (const unsigned*)hP_lo[cur], annotation, startg, endg, mg, invg, readout);
  k_logits<<<1, 64, 0, stream>>>(readout, out_w, out_b, labels, (float*)d_out, B);
}